// Round 8
// baseline (347.695 us; speedup 1.0000x reference)
//
#include <hip/hip_runtime.h>
#include <math.h>

// Problem constants (B,S,D,H) = (8, 2048, 1024, 4), HD = 256
#define BB 8
#define SS 2048
#define DD 1024
#define HH 4
#define HDD 256
#define NROW (BB*SS)           // 16384

// k1: wave-per-row, 16 rows/block (4 rows per wave), 1024 blocks
#define G1 16
#define NS1 (NROW/G1)          // 1024 slices
// k3: 8 rows/block, 2048 blocks
#define G3 8

// ws layout (float offsets), ~8.7 MB
#define W_MU_T 0
#define W_RS_T NROW
#define W_MU_I (2*NROW)
#define W_RS_I (3*NROW)
#define W_PT   (4*NROW)                 // [NS1][DD] text-global partials
#define W_PI   (W_PT + NS1*DD)          // [NS1][DD] image-global partials
#define W_PS   (W_PI + NS1*DD)          // [NS1] sim partials
#define W_TG   (W_PS + NS1)             // [B][D]
#define W_IG   (W_TG + BB*DD)           // [B][D]
#define W_SIM  (W_IG + BB*DD)           // [B]
#define W_LOGIT (W_SIM + BB)            // [B]

__device__ __forceinline__ float wred(float v) {
#pragma unroll
  for (int m = 32; m > 0; m >>= 1) v += __shfl_xor(v, m, 64);
  return v;
}
__device__ __forceinline__ float hsum(const float4 v) { return v.x+v.y+v.z+v.w; }
__device__ __forceinline__ float hsq(const float4 v)  { return v.x*v.x+v.y*v.y+v.z*v.z+v.w*v.w; }
__device__ __forceinline__ float hdot(const float4 a, const float4 b) {
  return a.x*b.x + a.y*b.y + a.z*b.z + a.w*b.w;
}

// =====================================================================
// k1 v2: wave-per-row stats — ZERO block barriers in the row loop (all
// row reductions are in-wave shuffles), next-row prefetch double-buffer.
// __launch_bounds__(256,4) caps VGPR at 128 -> 16 waves/CU (the fused
// experiment proved this structure fits 128 VGPR; its 8-wave/CU occupancy
// was the bottleneck we remove here).
// =====================================================================
__global__ __launch_bounds__(256, 4) void k1_stats2(
    const float* __restrict__ text, const float* __restrict__ image,
    const float* __restrict__ wt, const float* __restrict__ bt,
    const float* __restrict__ wi, const float* __restrict__ bi,
    float* __restrict__ ws)
{
  const int blk  = blockIdx.x;
  const int tid  = threadIdx.x;
  const int lane = tid & 63;
  const int wv   = tid >> 6;

  __shared__ float sAcc[2][4][DD];     // 32 KB: per-wave partial combine
  __shared__ float ssim[4];

  const int cb = lane << 2;            // col base within each 256-col chunk
  float4 Wt[4], Bt[4], Wi4[4], Bi4[4];
#pragma unroll
  for (int j = 0; j < 4; ++j) {
    Wt[j]  = *(const float4*)(wt + j*256 + cb);
    Bt[j]  = *(const float4*)(bt + j*256 + cb);
    Wi4[j] = *(const float4*)(wi + j*256 + cb);
    Bi4[j] = *(const float4*)(bi + j*256 + cb);
  }
  float4 tga[4], iga[4];
#pragma unroll
  for (int j = 0; j < 4; ++j) {
    tga[j] = make_float4(0.f,0.f,0.f,0.f);
    iga[j] = make_float4(0.f,0.f,0.f,0.f);
  }
  float sim_loc = 0.f;
  const float invD = 1.f/DD;
  const int rbase = blk*G1 + wv*4;     // this wave's 4 rows

  float4 tb[2][4], ib[2][4];           // double-buffered row registers
  {
    const float* tr = text  + (size_t)rbase*DD + cb;
    const float* ir = image + (size_t)rbase*DD + cb;
#pragma unroll
    for (int j = 0; j < 4; ++j) {
      tb[0][j] = *(const float4*)(tr + j*256);
      ib[0][j] = *(const float4*)(ir + j*256);
    }
  }

#pragma unroll 2
  for (int r = 0; r < 4; ++r) {
    const int cur = r & 1, nxt = cur ^ 1;   // compile-time after unroll 2
    if (r < 3) {                       // prefetch next row under this row's work
      const float* tr = text  + (size_t)(rbase + r + 1)*DD + cb;
      const float* ir = image + (size_t)(rbase + r + 1)*DD + cb;
#pragma unroll
      for (int j = 0; j < 4; ++j) {
        tb[nxt][j] = *(const float4*)(tr + j*256);
        ib[nxt][j] = *(const float4*)(ir + j*256);
      }
    }

    float st=0.f, qt=0.f, si=0.f, qi=0.f;
#pragma unroll
    for (int j = 0; j < 4; ++j) {
      st += hsum(tb[cur][j]);  qt += hsq(tb[cur][j]);
      si += hsum(ib[cur][j]);  qi += hsq(ib[cur][j]);
    }
    st = wred(st); qt = wred(qt); si = wred(si); qi = wred(qi);
    const float mt = st*invD, rt = rsqrtf(qt*invD - mt*mt + 1e-5f);
    const float mi = si*invD, ri = rsqrtf(qi*invD - mi*mi + 1e-5f);
    if (lane == 0) {
      const int row = rbase + r;
      ws[W_MU_T+row]=mt; ws[W_RS_T+row]=rt;
      ws[W_MU_I+row]=mi; ws[W_RS_I+row]=ri;
    }

    float dot=0.f, nt=0.f, ni=0.f;
#pragma unroll
    for (int j = 0; j < 4; ++j) {
      float4 tn, iv;
      tn.x = (tb[cur][j].x-mt)*rt*Wt[j].x + Bt[j].x;
      tn.y = (tb[cur][j].y-mt)*rt*Wt[j].y + Bt[j].y;
      tn.z = (tb[cur][j].z-mt)*rt*Wt[j].z + Bt[j].z;
      tn.w = (tb[cur][j].w-mt)*rt*Wt[j].w + Bt[j].w;
      iv.x = (ib[cur][j].x-mi)*ri*Wi4[j].x + Bi4[j].x;
      iv.y = (ib[cur][j].y-mi)*ri*Wi4[j].y + Bi4[j].y;
      iv.z = (ib[cur][j].z-mi)*ri*Wi4[j].z + Bi4[j].z;
      iv.w = (ib[cur][j].w-mi)*ri*Wi4[j].w + Bi4[j].w;
      tga[j].x += tn.x; tga[j].y += tn.y; tga[j].z += tn.z; tga[j].w += tn.w;
      iga[j].x += iv.x; iga[j].y += iv.y; iga[j].z += iv.z; iga[j].w += iv.w;
      dot += hdot(tn, iv); nt += hsq(tn); ni += hsq(iv);
    }
    dot = wred(dot); nt = wred(nt); ni = wred(ni);
    sim_loc += dot / (fmaxf(sqrtf(nt),1e-6f) * fmaxf(sqrtf(ni),1e-6f));
  }

  // Block-combine the 4 waves' global partials via LDS (one barrier total).
#pragma unroll
  for (int j = 0; j < 4; ++j) {
    *(float4*)&sAcc[0][wv][j*256 + cb] = tga[j];
    *(float4*)&sAcc[1][wv][j*256 + cb] = iga[j];
  }
  if (lane == 0) ssim[wv] = sim_loc;
  __syncthreads();

  const int c0 = tid << 2;
  float4 vt = make_float4(0.f,0.f,0.f,0.f);
  float4 vi = make_float4(0.f,0.f,0.f,0.f);
#pragma unroll
  for (int w = 0; w < 4; ++w) {
    const float4 a = *(const float4*)&sAcc[0][w][c0];
    vt.x += a.x; vt.y += a.y; vt.z += a.z; vt.w += a.w;
    const float4 e = *(const float4*)&sAcc[1][w][c0];
    vi.x += e.x; vi.y += e.y; vi.z += e.z; vi.w += e.w;
  }
  *(float4*)(ws + W_PT + (size_t)blk*DD + c0) = vt;
  *(float4*)(ws + W_PI + (size_t)blk*DD + c0) = vi;
  if (tid == 0) ws[W_PS + blk] = ssim[0]+ssim[1]+ssim[2]+ssim[3];
}

// Reduce 1024 partial slices. Blocks 0..255: (batch, 32-col chunk); each
// slice-group sums 16 slices, LDS tree over 8 groups. Block 256: sim + LOGIT=0.
__global__ __launch_bounds__(256) void kR_reduce2(float* __restrict__ ws)
{
  const int tid = threadIdx.x;
  if (blockIdx.x < 256) {
    const int b   = blockIdx.x >> 5;       // 0..7
    const int ch  = blockIdx.x & 31;       // 32-col chunk
    const int cl  = tid & 31;
    const int sg  = tid >> 5;              // 0..7 slice-group (16 slices each)
    const int col = ch*32 + cl;
    const float* pt = ws + W_PT + (size_t)(b*128 + sg*16)*DD + col;
    const float* pi = ws + W_PI + (size_t)(b*128 + sg*16)*DD + col;
    float at = 0.f, ai = 0.f;
#pragma unroll 4
    for (int k = 0; k < 16; ++k) {
      at += pt[(size_t)k*DD];
      ai += pi[(size_t)k*DD];
    }
    __shared__ float sred[2][8][32];
    sred[0][sg][cl] = at;
    sred[1][sg][cl] = ai;
    __syncthreads();
    if (tid < 32) {
      float v = 0.f;
#pragma unroll
      for (int q = 0; q < 8; ++q) v += sred[0][q][tid];
      ws[W_TG + b*DD + ch*32 + tid] = v;
    } else if (tid < 64) {
      const int c = tid - 32;
      float v = 0.f;
#pragma unroll
      for (int q = 0; q < 8; ++q) v += sred[1][q][c];
      ws[W_IG + b*DD + ch*32 + c] = v;
    }
  } else {
    __shared__ float sred[256];
    const int b = tid >> 5, j = tid & 31;
    float a = 0.f;
#pragma unroll
    for (int k = 0; k < 4; ++k) a += ws[W_PS + b*128 + j*4 + k];
    sred[tid] = a;
    __syncthreads();
    if (j == 0) {
      float s = 0.f;
#pragma unroll
      for (int m = 0; m < 32; ++m) s += sred[b*32 + m];
      ws[W_SIM + b] = s;
    }
    if (tid < BB) ws[W_LOGIT + tid] = 0.f;   // completes before k2 (stream order)
  }
}

// Gate network: 256 blocks, each owns 4 (h,k) rows (proven ~5us structure).
__global__ __launch_bounds__(256) void k2_gates(
    const float* __restrict__ Wa, const float* __restrict__ Wab,
    const float* __restrict__ Wq, const float* __restrict__ Wqb,
    const float* __restrict__ simw, const float* __restrict__ simb,
    const float* __restrict__ fcw, float* __restrict__ ws)
{
  const int tid  = threadIdx.x;
  const int lane = tid & 63;
  const int wv   = tid >> 6;
  const int r0   = blockIdx.x * 4;       // flat (h,k) row base, 0..1023
  const int d0   = tid << 2;

  __shared__ float red[4][4][BB];        // [row][wave][b]

  for (int rr = 0; rr < 4; ++rr) {
    const int r = r0 + rr;
    const float4 a4 = *(const float4*)(Wa + (size_t)r*DD + d0);
    const float4 q4 = *(const float4*)(Wq + (size_t)r*DD + d0);
    float acc[BB];
#pragma unroll
    for (int b = 0; b < BB; ++b) {
      const float4 t = *(const float4*)(ws + W_TG + b*DD + d0);
      const float4 i = *(const float4*)(ws + W_IG + b*DD + d0);
      acc[b] = hdot(a4, t) + hdot(q4, i);
    }
#pragma unroll
    for (int b = 0; b < BB; ++b) {
      acc[b] = wred(acc[b]);
      if (lane == 0) red[rr][wv][b] = acc[b];
    }
  }
  __syncthreads();
  if (tid < BB) {
    const int b = tid;
    const float inv = 1.f/SS;
    const float gs = ws[W_SIM + b] * inv;
    float part = 0.f;
#pragma unroll
    for (int rr = 0; rr < 4; ++rr) {
      const int r = r0 + rr;
      const int k = r & 255;
      const float v = (red[rr][0][b] + red[rr][1][b] + red[rr][2][b] + red[rr][3][b]) * inv;
      float gate = v + Wab[r] + Wqb[r] + gs*simw[k] + simb[k];
      gate = fmaxf(gate, 0.f);
      part += gate * fcw[r];
    }
    atomicAdd(&ws[W_LOGIT + b], part);
  }
}

// k3 v2: 8 rows per block, two 4-row groups with cross-group prefetch.
__global__ __launch_bounds__(256, 4) void k3_blend2(
    const float* __restrict__ text, const float* __restrict__ image,
    const float* __restrict__ wt, const float* __restrict__ bt,
    const float* __restrict__ wi, const float* __restrict__ bi,
    const float* __restrict__ fcb,
    const float* __restrict__ ws, float* __restrict__ out)
{
  const int r0 = blockIdx.x * G3;
  const int b  = r0 >> 11;      // same batch for all 8 rows
  const int d0 = threadIdx.x << 2;

  const float4 wt4 = *(const float4*)(wt + d0);
  const float4 bt4 = *(const float4*)(bt + d0);
  const float4 wi4 = *(const float4*)(wi + d0);
  const float4 bi4 = *(const float4*)(bi + d0);

  float4 tg[2][4], ig[2][4];
#pragma unroll
  for (int r = 0; r < 4; ++r) {
    tg[0][r] = *(const float4*)(text  + (size_t)(r0+r)*DD + d0);
    ig[0][r] = *(const float4*)(image + (size_t)(r0+r)*DD + d0);
  }

  const float g  = 1.f / (1.f + expf(-(ws[W_LOGIT+b] + fcb[0])));
  const float gi = 1.f - g;

#pragma unroll 2
  for (int gidx = 0; gidx < 2; ++gidx) {
    const int cur = gidx & 1, nxt = cur ^ 1;
    if (gidx < 1) {
      const int nr = r0 + 4;
#pragma unroll
      for (int r = 0; r < 4; ++r) {
        tg[nxt][r] = *(const float4*)(text  + (size_t)(nr+r)*DD + d0);
        ig[nxt][r] = *(const float4*)(image + (size_t)(nr+r)*DD + d0);
      }
    }
    const int rr = gidx*4;
#pragma unroll
    for (int r = 0; r < 4; ++r) {
      const int row = r0 + rr + r;
      const float mt = ws[W_MU_T+row], rt = ws[W_RS_T+row];
      const float mi = ws[W_MU_I+row], ri = ws[W_RS_I+row];
      const float gt = g*rt, gii = gi*ri;
      float4 o;
      o.x = gt*(tg[cur][r].x-mt)*wt4.x + g*bt4.x + gii*(ig[cur][r].x-mi)*wi4.x + gi*bi4.x;
      o.y = gt*(tg[cur][r].y-mt)*wt4.y + g*bt4.y + gii*(ig[cur][r].y-mi)*wi4.y + gi*bi4.y;
      o.z = gt*(tg[cur][r].z-mt)*wt4.z + g*bt4.z + gii*(ig[cur][r].z-mi)*wi4.z + gi*bi4.z;
      o.w = gt*(tg[cur][r].w-mt)*wt4.w + g*bt4.w + gii*(ig[cur][r].w-mi)*wi4.w + gi*bi4.w;
      *(float4*)(out + (size_t)row*DD + d0) = o;
    }
  }
}

extern "C" void kernel_launch(void* const* d_in, const int* in_sizes, int n_in,
                              void* d_out, int out_size, void* d_ws, size_t ws_size,
                              hipStream_t stream)
{
  const float* text   = (const float*)d_in[0];
  const float* image  = (const float*)d_in[1];
  const float* ln_t_w = (const float*)d_in[2];
  const float* ln_t_b = (const float*)d_in[3];
  const float* ln_i_w = (const float*)d_in[4];
  const float* ln_i_b = (const float*)d_in[5];
  const float* Wa     = (const float*)d_in[6];
  const float* Wab    = (const float*)d_in[7];
  const float* Wq     = (const float*)d_in[8];
  const float* Wqb    = (const float*)d_in[9];
  const float* simw   = (const float*)d_in[10];
  const float* simb   = (const float*)d_in[11];
  const float* fcw    = (const float*)d_in[12];
  const float* fcb    = (const float*)d_in[13];
  float* ws  = (float*)d_ws;
  float* out = (float*)d_out;

  k1_stats2<<<NS1, 256, 0, stream>>>(text, image, ln_t_w, ln_t_b, ln_i_w, ln_i_b, ws);
  kR_reduce2<<<257, 256, 0, stream>>>(ws);
  k2_gates<<<HH*HDD/4, 256, 0, stream>>>(Wa, Wab, Wq, Wqb, simw, simb, fcw, ws);
  k3_blend2<<<NROW/G3, 256, 0, stream>>>(text, image, ln_t_w, ln_t_b, ln_i_w, ln_i_b, fcb, ws, out);
}

// Round 9
// 241.030 us; speedup vs baseline: 1.4425x; 1.4425x over previous
//
#include <hip/hip_runtime.h>
#include <math.h>

// Problem constants (B,S,D,H) = (8, 2048, 1024, 4), HD = 256
#define BB 8
#define SS 2048
#define DD 1024
#define HH 4
#define HDD 256
#define NROW (BB*SS)           // 16384

// k1: wave-per-row, 16 rows/block (4 rows per wave), 1024 blocks
#define G1 16
#define NS1 (NROW/G1)          // 1024 slices

// ws layout (float offsets), ~8.7 MB
#define W_MU_T 0
#define W_RS_T NROW
#define W_MU_I (2*NROW)
#define W_RS_I (3*NROW)
#define W_PT   (4*NROW)                 // [NS1][DD] text-global partials
#define W_PI   (W_PT + NS1*DD)          // [NS1][DD] image-global partials
#define W_PS   (W_PI + NS1*DD)          // [NS1] sim partials
#define W_TG   (W_PS + NS1)             // [B][D]
#define W_IG   (W_TG + BB*DD)           // [B][D]
#define W_SIM  (W_IG + BB*DD)           // [B]
#define W_LOGIT (W_SIM + BB)            // [B]

__device__ __forceinline__ float wred(float v) {
#pragma unroll
  for (int m = 32; m > 0; m >>= 1) v += __shfl_xor(v, m, 64);
  return v;
}
__device__ __forceinline__ float hsum(const float4 v) { return v.x+v.y+v.z+v.w; }
__device__ __forceinline__ float hsq(const float4 v)  { return v.x*v.x+v.y*v.y+v.z*v.z+v.w*v.w; }
__device__ __forceinline__ float hdot(const float4 a, const float4 b) {
  return a.x*b.x + a.y*b.y + a.z*b.z + a.w*b.w;
}

// =====================================================================
// k1: wave-per-row stats — zero block barriers in the row loop, next-row
// register double-buffer.  NO min-waves launch bound: the kernel's live
// state is ~160 VGPR; capping it (round 8's (256,4) -> 64 VGPR) produced
// ~350 MB of scratch-spill traffic.  Compiler-chosen VGPR (~160) gives
// 3 waves/SIMD spill-free.
// =====================================================================
__global__ __launch_bounds__(256) void k1_stats2(
    const float* __restrict__ text, const float* __restrict__ image,
    const float* __restrict__ wt, const float* __restrict__ bt,
    const float* __restrict__ wi, const float* __restrict__ bi,
    float* __restrict__ ws)
{
  const int blk  = blockIdx.x;
  const int tid  = threadIdx.x;
  const int lane = tid & 63;
  const int wv   = tid >> 6;

  __shared__ float sAcc[2][4][DD];     // 32 KB: per-wave partial combine
  __shared__ float ssim[4];

  const int cb = lane << 2;            // col base within each 256-col chunk
  float4 Wt[4], Bt[4], Wi4[4], Bi4[4];
#pragma unroll
  for (int j = 0; j < 4; ++j) {
    Wt[j]  = *(const float4*)(wt + j*256 + cb);
    Bt[j]  = *(const float4*)(bt + j*256 + cb);
    Wi4[j] = *(const float4*)(wi + j*256 + cb);
    Bi4[j] = *(const float4*)(bi + j*256 + cb);
  }
  float4 tga[4], iga[4];
#pragma unroll
  for (int j = 0; j < 4; ++j) {
    tga[j] = make_float4(0.f,0.f,0.f,0.f);
    iga[j] = make_float4(0.f,0.f,0.f,0.f);
  }
  float sim_loc = 0.f;
  const float invD = 1.f/DD;
  const int rbase = blk*G1 + wv*4;     // this wave's 4 rows

  float4 tb[2][4], ib[2][4];           // double-buffered row registers
  {
    const float* tr = text  + (size_t)rbase*DD + cb;
    const float* ir = image + (size_t)rbase*DD + cb;
#pragma unroll
    for (int j = 0; j < 4; ++j) {
      tb[0][j] = *(const float4*)(tr + j*256);
      ib[0][j] = *(const float4*)(ir + j*256);
    }
  }

#pragma unroll 2
  for (int r = 0; r < 4; ++r) {
    const int cur = r & 1, nxt = cur ^ 1;   // compile-time after unroll 2
    if (r < 3) {                       // prefetch next row under this row's work
      const float* tr = text  + (size_t)(rbase + r + 1)*DD + cb;
      const float* ir = image + (size_t)(rbase + r + 1)*DD + cb;
#pragma unroll
      for (int j = 0; j < 4; ++j) {
        tb[nxt][j] = *(const float4*)(tr + j*256);
        ib[nxt][j] = *(const float4*)(ir + j*256);
      }
    }

    float st=0.f, qt=0.f, si=0.f, qi=0.f;
#pragma unroll
    for (int j = 0; j < 4; ++j) {
      st += hsum(tb[cur][j]);  qt += hsq(tb[cur][j]);
      si += hsum(ib[cur][j]);  qi += hsq(ib[cur][j]);
    }
    st = wred(st); qt = wred(qt); si = wred(si); qi = wred(qi);
    const float mt = st*invD, rt = rsqrtf(qt*invD - mt*mt + 1e-5f);
    const float mi = si*invD, ri = rsqrtf(qi*invD - mi*mi + 1e-5f);
    if (lane == 0) {
      const int row = rbase + r;
      ws[W_MU_T+row]=mt; ws[W_RS_T+row]=rt;
      ws[W_MU_I+row]=mi; ws[W_RS_I+row]=ri;
    }

    float dot=0.f, nt=0.f, ni=0.f;
#pragma unroll
    for (int j = 0; j < 4; ++j) {
      float4 tn, iv;
      tn.x = (tb[cur][j].x-mt)*rt*Wt[j].x + Bt[j].x;
      tn.y = (tb[cur][j].y-mt)*rt*Wt[j].y + Bt[j].y;
      tn.z = (tb[cur][j].z-mt)*rt*Wt[j].z + Bt[j].z;
      tn.w = (tb[cur][j].w-mt)*rt*Wt[j].w + Bt[j].w;
      iv.x = (ib[cur][j].x-mi)*ri*Wi4[j].x + Bi4[j].x;
      iv.y = (ib[cur][j].y-mi)*ri*Wi4[j].y + Bi4[j].y;
      iv.z = (ib[cur][j].z-mi)*ri*Wi4[j].z + Bi4[j].z;
      iv.w = (ib[cur][j].w-mi)*ri*Wi4[j].w + Bi4[j].w;
      tga[j].x += tn.x; tga[j].y += tn.y; tga[j].z += tn.z; tga[j].w += tn.w;
      iga[j].x += iv.x; iga[j].y += iv.y; iga[j].z += iv.z; iga[j].w += iv.w;
      dot += hdot(tn, iv); nt += hsq(tn); ni += hsq(iv);
    }
    dot = wred(dot); nt = wred(nt); ni = wred(ni);
    sim_loc += dot / (fmaxf(sqrtf(nt),1e-6f) * fmaxf(sqrtf(ni),1e-6f));
  }

  // Block-combine the 4 waves' global partials via LDS (one barrier total).
#pragma unroll
  for (int j = 0; j < 4; ++j) {
    *(float4*)&sAcc[0][wv][j*256 + cb] = tga[j];
    *(float4*)&sAcc[1][wv][j*256 + cb] = iga[j];
  }
  if (lane == 0) ssim[wv] = sim_loc;
  __syncthreads();

  const int c0 = tid << 2;
  float4 vt = make_float4(0.f,0.f,0.f,0.f);
  float4 vi = make_float4(0.f,0.f,0.f,0.f);
#pragma unroll
  for (int w = 0; w < 4; ++w) {
    const float4 a = *(const float4*)&sAcc[0][w][c0];
    vt.x += a.x; vt.y += a.y; vt.z += a.z; vt.w += a.w;
    const float4 e = *(const float4*)&sAcc[1][w][c0];
    vi.x += e.x; vi.y += e.y; vi.z += e.z; vi.w += e.w;
  }
  *(float4*)(ws + W_PT + (size_t)blk*DD + c0) = vt;
  *(float4*)(ws + W_PI + (size_t)blk*DD + c0) = vi;
  if (tid == 0) ws[W_PS + blk] = ssim[0]+ssim[1]+ssim[2]+ssim[3];
}

// Reduce 1024 partial slices. Blocks 0..255: (batch, 32-col chunk); each
// slice-group sums 16 slices, LDS tree over 8 groups. Block 256: sim + LOGIT=0.
__global__ __launch_bounds__(256) void kR_reduce2(float* __restrict__ ws)
{
  const int tid = threadIdx.x;
  if (blockIdx.x < 256) {
    const int b   = blockIdx.x >> 5;       // 0..7
    const int ch  = blockIdx.x & 31;       // 32-col chunk
    const int cl  = tid & 31;
    const int sg  = tid >> 5;              // 0..7 slice-group (16 slices each)
    const int col = ch*32 + cl;
    const float* pt = ws + W_PT + (size_t)(b*128 + sg*16)*DD + col;
    const float* pi = ws + W_PI + (size_t)(b*128 + sg*16)*DD + col;
    float at = 0.f, ai = 0.f;
#pragma unroll 4
    for (int k = 0; k < 16; ++k) {
      at += pt[(size_t)k*DD];
      ai += pi[(size_t)k*DD];
    }
    __shared__ float sred[2][8][32];
    sred[0][sg][cl] = at;
    sred[1][sg][cl] = ai;
    __syncthreads();
    if (tid < 32) {
      float v = 0.f;
#pragma unroll
      for (int q = 0; q < 8; ++q) v += sred[0][q][tid];
      ws[W_TG + b*DD + ch*32 + tid] = v;
    } else if (tid < 64) {
      const int c = tid - 32;
      float v = 0.f;
#pragma unroll
      for (int q = 0; q < 8; ++q) v += sred[1][q][c];
      ws[W_IG + b*DD + ch*32 + c] = v;
    }
  } else {
    __shared__ float sred[256];
    const int b = tid >> 5, j = tid & 31;
    float a = 0.f;
#pragma unroll
    for (int k = 0; k < 4; ++k) a += ws[W_PS + b*128 + j*4 + k];
    sred[tid] = a;
    __syncthreads();
    if (j == 0) {
      float s = 0.f;
#pragma unroll
      for (int m = 0; m < 32; ++m) s += sred[b*32 + m];
      ws[W_SIM + b] = s;
    }
    if (tid < BB) ws[W_LOGIT + tid] = 0.f;   // completes before k2 (stream order)
  }
}

// Gate network: 256 blocks, each owns 4 (h,k) rows (proven ~5us structure).
__global__ __launch_bounds__(256) void k2_gates(
    const float* __restrict__ Wa, const float* __restrict__ Wab,
    const float* __restrict__ Wq, const float* __restrict__ Wqb,
    const float* __restrict__ simw, const float* __restrict__ simb,
    const float* __restrict__ fcw, float* __restrict__ ws)
{
  const int tid  = threadIdx.x;
  const int lane = tid & 63;
  const int wv   = tid >> 6;
  const int r0   = blockIdx.x * 4;       // flat (h,k) row base, 0..1023
  const int d0   = tid << 2;

  __shared__ float red[4][4][BB];        // [row][wave][b]

  for (int rr = 0; rr < 4; ++rr) {
    const int r = r0 + rr;
    const float4 a4 = *(const float4*)(Wa + (size_t)r*DD + d0);
    const float4 q4 = *(const float4*)(Wq + (size_t)r*DD + d0);
    float acc[BB];
#pragma unroll
    for (int b = 0; b < BB; ++b) {
      const float4 t = *(const float4*)(ws + W_TG + b*DD + d0);
      const float4 i = *(const float4*)(ws + W_IG + b*DD + d0);
      acc[b] = hdot(a4, t) + hdot(q4, i);
    }
#pragma unroll
    for (int b = 0; b < BB; ++b) {
      acc[b] = wred(acc[b]);
      if (lane == 0) red[rr][wv][b] = acc[b];
    }
  }
  __syncthreads();
  if (tid < BB) {
    const int b = tid;
    const float inv = 1.f/SS;
    const float gs = ws[W_SIM + b] * inv;
    float part = 0.f;
#pragma unroll
    for (int rr = 0; rr < 4; ++rr) {
      const int r = r0 + rr;
      const int k = r & 255;
      const float v = (red[rr][0][b] + red[rr][1][b] + red[rr][2][b] + red[rr][3][b]) * inv;
      float gate = v + Wab[r] + Wqb[r] + gs*simw[k] + simb[k];
      gate = fmaxf(gate, 0.f);
      part += gate * fcw[r];
    }
    atomicAdd(&ws[W_LOGIT + b], part);
  }
}

// k3: round-0 proven blend — 4 rows/block, all 8 loads issued before compute,
// ~52 VGPR, no dbuf (high natural occupancy, no spill risk).
__global__ __launch_bounds__(256) void k3_blend(
    const float* __restrict__ text, const float* __restrict__ image,
    const float* __restrict__ wt, const float* __restrict__ bt,
    const float* __restrict__ wi, const float* __restrict__ bi,
    const float* __restrict__ fcb,
    const float* __restrict__ ws, float* __restrict__ out)
{
  const int r0 = blockIdx.x * 4;
  const int b  = r0 >> 11;      // same b for all 4 rows
  const int d0 = threadIdx.x << 2;

  float4 t[4], im[4];
#pragma unroll
  for (int r = 0; r < 4; ++r) {
    t[r]  = *(const float4*)(text  + (size_t)(r0+r)*DD + d0);
    im[r] = *(const float4*)(image + (size_t)(r0+r)*DD + d0);
  }
  const float4 wt4 = *(const float4*)(wt + d0);
  const float4 bt4 = *(const float4*)(bt + d0);
  const float4 wi4 = *(const float4*)(wi + d0);
  const float4 bi4 = *(const float4*)(bi + d0);

  const float g  = 1.f / (1.f + expf(-(ws[W_LOGIT+b] + fcb[0])));
  const float gi = 1.f - g;

#pragma unroll
  for (int r = 0; r < 4; ++r) {
    const float mt = ws[W_MU_T+r0+r], rt = ws[W_RS_T+r0+r];
    const float mi = ws[W_MU_I+r0+r], ri = ws[W_RS_I+r0+r];
    const float gt = g*rt, gii = gi*ri;
    float4 o;
    o.x = gt*(t[r].x-mt)*wt4.x + g*bt4.x + gii*(im[r].x-mi)*wi4.x + gi*bi4.x;
    o.y = gt*(t[r].y-mt)*wt4.y + g*bt4.y + gii*(im[r].y-mi)*wi4.y + gi*bi4.y;
    o.z = gt*(t[r].z-mt)*wt4.z + g*bt4.z + gii*(im[r].z-mi)*wi4.z + gi*bi4.z;
    o.w = gt*(t[r].w-mt)*wt4.w + g*bt4.w + gii*(im[r].w-mi)*wi4.w + gi*bi4.w;
    *(float4*)(out + (size_t)(r0+r)*DD + d0) = o;
  }
}

extern "C" void kernel_launch(void* const* d_in, const int* in_sizes, int n_in,
                              void* d_out, int out_size, void* d_ws, size_t ws_size,
                              hipStream_t stream)
{
  const float* text   = (const float*)d_in[0];
  const float* image  = (const float*)d_in[1];
  const float* ln_t_w = (const float*)d_in[2];
  const float* ln_t_b = (const float*)d_in[3];
  const float* ln_i_w = (const float*)d_in[4];
  const float* ln_i_b = (const float*)d_in[5];
  const float* Wa     = (const float*)d_in[6];
  const float* Wab    = (const float*)d_in[7];
  const float* Wq     = (const float*)d_in[8];
  const float* Wqb    = (const float*)d_in[9];
  const float* simw   = (const float*)d_in[10];
  const float* simb   = (const float*)d_in[11];
  const float* fcw    = (const float*)d_in[12];
  const float* fcb    = (const float*)d_in[13];
  float* ws  = (float*)d_ws;
  float* out = (float*)d_out;

  k1_stats2<<<NS1, 256, 0, stream>>>(text, image, ln_t_w, ln_t_b, ln_i_w, ln_i_b, ws);
  kR_reduce2<<<257, 256, 0, stream>>>(ws);
  k2_gates<<<HH*HDD/4, 256, 0, stream>>>(Wa, Wab, Wq, Wqb, simw, simb, fcw, ws);
  k3_blend<<<NROW/4, 256, 0, stream>>>(text, image, ln_t_w, ln_t_b, ln_i_w, ln_i_b, fcb, ws, out);
}